// Round 4
// baseline (241.516 us; speedup 1.0000x reference)
//
#include <hip/hip_runtime.h>

// IntraClusterGAT on MI355X — Round 10: kill the scatter atomics.
//   Diagnosis: 8.4M global_atomic_pk_add_bf16 (random 64B-line RMW at the LLC)
//   set the attn wall (~55 µs arithmetic = measured). All other pipes <30%.
//   Dense path (if ws_size >= ~47.2MB):
//     attn writes h densely to H[(c*128+row)*64] (plain coalesced stores);
//     build_index: per-node count + capacity-16 bucket of entry ids (262K int
//     atomics total); finalize gathers each node's entries, sums in fp32,
//     projects through P, divides by count.
//   Fallback path (ws too small): exact R9 atomic-scatter pipeline.
// ws (dense): H 33.55MB | icnt 0.8MB | buck 12.8MB | Mtr/Pbf 16KB  = 47.2MB
// ws (fallback): accum_bf 25.6MB | countv 0.8MB | Mtr/Pbf 16KB     = 27.2MB

#define NV 100000
#define NN 200000
#define NCLUST 2048
#define XS 72    // X/E row stride (bf16): 144B, 16B-aligned, conflict-free
#define BUCK_K 16

typedef __attribute__((ext_vector_type(8))) short short8;
typedef __attribute__((ext_vector_type(16))) float floatx16;

__device__ __forceinline__ unsigned short f2bf(float f) {
    union { float f; unsigned u; } v; v.f = f;
    unsigned r = v.u + 0x7fffu + ((v.u >> 16) & 1u);   // RNE
    return (unsigned short)(r >> 16);
}
__device__ __forceinline__ float bf2f(unsigned short s) {
    union { unsigned u; float f; } v; v.u = (unsigned)s << 16; return v.f;
}
__device__ __forceinline__ unsigned pack2bf(float lo, float hi) {
    union { float f; unsigned u; } a, b; a.f = lo; b.f = hi;
    unsigned ra = a.u + 0x7fffu + ((a.u >> 16) & 1u);
    unsigned rb = b.u + 0x7fffu + ((b.u >> 16) & 1u);
    return (ra >> 16) | (rb & 0xffff0000u);
}
__device__ __forceinline__ int crow(int r, int lane) {   // MFMA 32x32 C row map
    return (r & 3) + 8 * (r >> 2) + 4 * (lane >> 5);
}
template<int CTRL>
__device__ __forceinline__ unsigned dppmov(unsigned v) {
    return (unsigned)__builtin_amdgcn_update_dpp(0, (int)v, CTRL, 0xf, 0xf, true);
}
template<int CTRL>
__device__ __forceinline__ float dppaddf(float s) {      // s + dpp_rotated(s)
    union { float f; unsigned u; } a, b; a.f = s;
    b.u = dppmov<CTRL>(a.u);
    return s + b.f;
}
__device__ __forceinline__ float dppxor1f(float s) {
    union { float f; unsigned u; } a, b; a.f = s;
    b.u = dppmov<0xB1>(a.u);
    return b.f;
}
// Barrier that orders LDS only: waves drain their own DS ops, then s_barrier.
// Global stores/atomics intentionally stay in flight.
__device__ __forceinline__ void bar_lds() {
    __builtin_amdgcn_sched_barrier(0);
    asm volatile("s_waitcnt lgkmcnt(0)" ::: "memory");
    __builtin_amdgcn_s_barrier();
    __builtin_amdgcn_sched_barrier(0);
}

__global__ __launch_bounds__(256) void prep_kernel(
    const float* __restrict__ WQ, const float* __restrict__ WK,
    const float* __restrict__ WV, const float* __restrict__ Wout,
    const float* __restrict__ head_weights, const int* __restrict__ active_heads_p,
    unsigned short* __restrict__ Mtr, unsigned short* __restrict__ Pbf)
{
    int o = blockIdx.x * blockDim.x + threadIdx.x;
    int ah = active_heads_p[0];
    float hw = 0.f;
    for (int i = 0; i < ah; ++i) hw += head_weights[i];
    hw /= (float)ah;
    if (o < 4096) {
        int d = o >> 6, a = o & 63;                       // Mtr[d][a] = M[a][d]
        float acc = 0.f;
        for (int j = 0; j < 64; ++j) acc += WQ[j*64 + a] * WK[j*64 + d];
        Mtr[o] = f2bf(acc * 0.125f);
    } else if (o < 8192) {
        int o2 = o - 4096;
        int j = o2 >> 6, b = o2 & 63;                     // Pbf[j][b]
        float acc = 0.f;
        for (int d = 0; d < 64; ++d) acc += Wout[j*64 + d] * WV[d*64 + b];
        Pbf[o2] = f2bf(acc * hw);
    }
}

// Inverted index: entry e = c*128 + r belongs to node nid(e).
__global__ __launch_bounds__(256) void build_index_kernel(
    const int* __restrict__ cvar, const int* __restrict__ ccl,
    int* __restrict__ icnt, int* __restrict__ buck)
{
    int e = blockIdx.x * 256 + threadIdx.x;       // 0 .. 262143
    int c = e >> 7, r = e & 127;
    int nid = (r < 64) ? cvar[c * 64 + r] : (NV + ccl[c * 64 + (r - 64)]);
    int pos = atomicAdd(&icnt[nid], 1);
    if (pos < BUCK_K) buck[(size_t)nid * BUCK_K + pos] = e;
}

// Full per-cluster compute: GEMM1 -> GEMM2 -> softmax -> (E-half | GEMM3)x2
// -> [optional next-cluster X write into E buffer] -> h store (dense or atomic).
template<bool WN, bool DENSE>
__device__ __forceinline__ void cluster_compute(
    unsigned short* X, unsigned short* E,
    const int* ids, const float* biascl,
    const unsigned short* __restrict__ Mtr,
    unsigned short* __restrict__ sbase,    // DENSE: H + c*128*64 ; else accum_bf
    int lane, int w, int m, int hk, int r, int cb,
    short8 nx0, short8 nx1, short8 nx2, short8 nx3)
{
    // ---- GEMM1: Z = X @ M  (m-tile w, K=64; M frags from global/L1) ----
    {
        floatx16 z0 = {}, z1 = {};
        #pragma unroll
        for (int ks = 0; ks < 4; ++ks) {
            short8 mb0 = *(const short8*)(Mtr + m * 64 + ks * 16 + hk);
            short8 mb1 = *(const short8*)(Mtr + (32 + m) * 64 + ks * 16 + hk);
            short8 a = *(const short8*)&X[(w * 32 + m) * XS + ks * 16 + hk];
            z0 = __builtin_amdgcn_mfma_f32_32x32x16_bf16(a, mb0, z0, 0, 0, 0);
            z1 = __builtin_amdgcn_mfma_f32_32x32x16_bf16(a, mb1, z1, 0, 0, 0);
        }
        #pragma unroll
        for (int rr = 0; rr < 16; ++rr) {   // wave-local rows 32w..32w+31
            int row = w * 32 + crow(rr, lane);
            E[row * XS + m]      = f2bf(z0[rr]);
            E[row * XS + 32 + m] = f2bf(z1[rr]);
        }
    }

    // ---- GEMM2: scores = Z @ X^T  (m-tile w, n-tiles 0..3, K=64) ----
    floatx16 sc[4] = {{}, {}, {}, {}};
    #pragma unroll
    for (int ks = 0; ks < 4; ++ks) {
        short8 a = *(const short8*)&E[(w * 32 + m) * XS + ks * 16 + hk];
        #pragma unroll
        for (int nt = 0; nt < 4; ++nt) {
            short8 b = *(const short8*)&X[(nt * 32 + m) * XS + ks * 16 + hk];
            sc[nt] = __builtin_amdgcn_mfma_f32_32x32x16_bf16(a, b, sc[nt], 0, 0, 0);
        }
    }

    // ---- bias + leaky_relu + exp + rowsum (DPP ror x4 + 1 swizzle) ----
    const float b2 = biascl[m], b3 = biascl[32 + m];
    #pragma unroll
    for (int rr = 0; rr < 16; ++rr) {
        float a0 = sc[0][rr], a1 = sc[1][rr], a2 = sc[2][rr] + b2, a3 = sc[3][rr] + b3;
        a0 = a0 > 0.f ? a0 : 0.2f * a0;
        a1 = a1 > 0.f ? a1 : 0.2f * a1;
        a2 = a2 > 0.f ? a2 : 0.2f * a2;
        a3 = a3 > 0.f ? a3 : 0.2f * a3;
        a0 = __expf(a0); a1 = __expf(a1); a2 = __expf(a2); a3 = __expf(a3);
        float s4 = (a0 + a1) + (a2 + a3);       // row's 32-col partial per lane
        s4 = dppaddf<0x121>(s4);                // + ror1   (16-lane row, VALU)
        s4 = dppaddf<0x122>(s4);                // + ror2
        s4 = dppaddf<0x124>(s4);                // + ror4
        s4 = dppaddf<0x128>(s4);                // + ror8 -> 16-lane sum everywhere
        {   // cross-16 within each 32-lane half: one ds_swizzle xor16
            union { float f; int i; } t, o; t.f = s4;
            o.i = __builtin_amdgcn_ds_swizzle(t.i, 0x401F);
            s4 += o.f;
        }
        float inv = __builtin_amdgcn_rcpf(s4);  // full 128-col rowsum (half-wave)
        sc[0][rr] = a0 * inv; sc[1][rr] = a1 * inv;
        sc[2][rr] = a2 * inv; sc[3][rr] = a3 * inv;
    }

    // ---- E-half 1 (cols 0..63) over Z rows (wave-local; in-order DS) ----
    #pragma unroll
    for (int rr = 0; rr < 16; ++rr) {
        int row = w * 32 + crow(rr, lane);
        E[row * XS + m]      = f2bf(sc[0][rr]);
        E[row * XS + 32 + m] = f2bf(sc[1][rr]);
    }

    // ---- GEMM3: B col-pairs via b32 loads (-> ds_read2_b32) + v_perm ----
    const int cp = m & ~1;                       // col-pair base
    const unsigned selp = (lane & 1) ? 0x07060302u : 0x05040100u;  // hi16 : lo16
    floatx16 g0 = {}, g1 = {};
    #pragma unroll
    for (int ks = 0; ks < 4; ++ks) {             // half 1: t = 0..63
        short8 a = *(const short8*)&E[(w * 32 + m) * XS + ks * 16 + hk];
        const unsigned short* tb = &X[(ks * 16 + hk) * XS];
        unsigned q0[8], q1[8];
        #pragma unroll
        for (int u = 0; u < 8; ++u) {
            q0[u] = *(const unsigned*)(tb + u * XS + cp);
            q1[u] = *(const unsigned*)(tb + u * XS + cp + 32);
        }
        union { unsigned u[4]; short8 v; } b0, b1;
        b0.u[0] = __builtin_amdgcn_perm(q0[1], q0[0], selp);
        b0.u[1] = __builtin_amdgcn_perm(q0[3], q0[2], selp);
        b0.u[2] = __builtin_amdgcn_perm(q0[5], q0[4], selp);
        b0.u[3] = __builtin_amdgcn_perm(q0[7], q0[6], selp);
        b1.u[0] = __builtin_amdgcn_perm(q1[1], q1[0], selp);
        b1.u[1] = __builtin_amdgcn_perm(q1[3], q1[2], selp);
        b1.u[2] = __builtin_amdgcn_perm(q1[5], q1[4], selp);
        b1.u[3] = __builtin_amdgcn_perm(q1[7], q1[6], selp);
        g0 = __builtin_amdgcn_mfma_f32_32x32x16_bf16(a, b0.v, g0, 0, 0, 0);
        g1 = __builtin_amdgcn_mfma_f32_32x32x16_bf16(a, b1.v, g1, 0, 0, 0);
    }

    // ---- E-half 2 (cols 64..127) ----
    #pragma unroll
    for (int rr = 0; rr < 16; ++rr) {
        int row = w * 32 + crow(rr, lane);
        E[row * XS + m]      = f2bf(sc[2][rr]);
        E[row * XS + 32 + m] = f2bf(sc[3][rr]);
    }

    // ---- GEMM3 half 2: t = 64..127 ----
    #pragma unroll
    for (int ks = 0; ks < 4; ++ks) {
        short8 a = *(const short8*)&E[(w * 32 + m) * XS + ks * 16 + hk];
        const unsigned short* tb = &X[(64 + ks * 16 + hk) * XS];
        unsigned q0[8], q1[8];
        #pragma unroll
        for (int u = 0; u < 8; ++u) {
            q0[u] = *(const unsigned*)(tb + u * XS + cp);
            q1[u] = *(const unsigned*)(tb + u * XS + cp + 32);
        }
        union { unsigned u[4]; short8 v; } b0, b1;
        b0.u[0] = __builtin_amdgcn_perm(q0[1], q0[0], selp);
        b0.u[1] = __builtin_amdgcn_perm(q0[3], q0[2], selp);
        b0.u[2] = __builtin_amdgcn_perm(q0[5], q0[4], selp);
        b0.u[3] = __builtin_amdgcn_perm(q0[7], q0[6], selp);
        b1.u[0] = __builtin_amdgcn_perm(q1[1], q1[0], selp);
        b1.u[1] = __builtin_amdgcn_perm(q1[3], q1[2], selp);
        b1.u[2] = __builtin_amdgcn_perm(q1[5], q1[4], selp);
        b1.u[3] = __builtin_amdgcn_perm(q1[7], q1[6], selp);
        g0 = __builtin_amdgcn_mfma_f32_32x32x16_bf16(a, b0.v, g0, 0, 0, 0);
        g1 = __builtin_amdgcn_mfma_f32_32x32x16_bf16(a, b1.v, g1, 0, 0, 0);
    }

    // ---- park next cluster's X rows into E (wave-local rows; DS in-order
    //      guarantees these land after this wave's last E A-reads above) ----
    if (WN) {
        *(short8*)&E[r * XS + cb +  0] = nx0;
        *(short8*)&E[r * XS + cb +  8] = nx1;
        *(short8*)&E[r * XS + cb + 16] = nx2;
        *(short8*)&E[r * XS + cb + 24] = nx3;
    }

    // ---- pack adjacent cols (DPP quad_perm xor1) + h store ----
    const bool ev = !(lane & 1);
    const int colbase = ev ? m : (31 + m);
    #pragma unroll
    for (int rr = 0; rr < 16; ++rr) {
        int row = w * 32 + crow(rr, lane);
        float a0 = g0[rr], a1 = g1[rr];
        float t0 = dppxor1f(a0);
        float t1 = dppxor1f(a1);
        float lo = ev ? a0 : t1;
        float hi = ev ? t0 : a1;
        unsigned pk = (unsigned)f2bf(lo) | ((unsigned)f2bf(hi) << 16);
        if constexpr (DENSE) {
            // dense H: entry (c,row) -> plain coalesced store, no atomics
            *(unsigned*)(sbase + (size_t)row * 64 + colbase) = pk;
        } else {
            int nid = ids[row];
            unsigned long long addr =
                (unsigned long long)(sbase + (size_t)nid * 64 + colbase);
            asm volatile("global_atomic_pk_add_bf16 %0, %1, off"
                         :: "v"(addr), "v"(pk) : "memory");
        }
    }
}

template<bool DENSE>
__global__ __launch_bounds__(256, 4) void attn_kernel(
    const float* __restrict__ x_var, const float* __restrict__ x_clause,
    const int* __restrict__ cvar, const int* __restrict__ ccl,
    const float* __restrict__ sat, const unsigned short* __restrict__ Mtr,
    unsigned short* __restrict__ Hacc, float* __restrict__ countv)
{
    __shared__ unsigned short bufA[128 * XS];  // 18432
    __shared__ unsigned short bufB[128 * XS];  // 18432
    __shared__ int   ids0[128], ids1[128];     // 1024 (fallback only)
    __shared__ float bias0[64], bias1[64];     // 512
    // total 38400 B -> 4 blocks/CU

    const int tid = threadIdx.x, lane = tid & 63, w = tid >> 6;
    const int m = lane & 31, hk = (lane >> 5) * 8;
    const int c0 = blockIdx.x * 2;             // this block owns c0, c0+1
    const int r = tid >> 1, half = tid & 1, cb = half * 32;

    // ---- ids for BOTH clusters (issued together -> one latency) ----
    int nid0, nid1;
    const float *src0, *src1;
    float sv0 = 0.f, sv1 = 0.f;
    if (r < 64) {
        nid0 = cvar[c0 * 64 + r];
        nid1 = cvar[c0 * 64 + 64 + r];         // cluster c0+1
        src0 = x_var + (size_t)nid0 * 64;
        src1 = x_var + (size_t)nid1 * 64;
    } else {
        int cid0 = ccl[c0 * 64 + (r - 64)];
        int cid1 = ccl[c0 * 64 + r];           // cluster c0+1
        nid0 = NV + cid0; nid1 = NV + cid1;
        src0 = x_clause + (size_t)cid0 * 64;
        src1 = x_clause + (size_t)cid1 * 64;
        if (half) { sv0 = sat[cid0]; sv1 = sat[cid1]; }
    }

    // ---- issue ALL 16 row loads (both clusters) back-to-back ----
    const float4* s40 = (const float4*)src0 + half * 8;
    const float4* s41 = (const float4*)src1 + half * 8;
    float4 v0[8], v1[8];
    #pragma unroll
    for (int i = 0; i < 8; ++i) v0[i] = s40[i];
    #pragma unroll
    for (int i = 0; i < 8; ++i) v1[i] = s41[i];

    if constexpr (!DENSE) {
        if (!half) {
            ids0[r] = nid0; ids1[r] = nid1;
            atomicAdd(&countv[nid0], 1.0f);
            atomicAdd(&countv[nid1], 1.0f);
        }
    }
    if (r >= 64 && half) { bias0[r - 64] = sv0; bias1[r - 64] = sv1; }

    // ---- c0 -> bufA (row-major bf16) ----
    {
        union { unsigned u[16]; short8 v[4]; } h0;
        #pragma unroll
        for (int i = 0; i < 8; ++i) {
            h0.u[2*i]   = pack2bf(v0[i].x, v0[i].y);
            h0.u[2*i+1] = pack2bf(v0[i].z, v0[i].w);
        }
        #pragma unroll
        for (int i = 0; i < 4; ++i) *(short8*)&bufA[r * XS + cb + i * 8] = h0.v[i];
    }
    // ---- c1 -> 16 packed VGPRs (held across c0 compute) ----
    union { unsigned u[16]; short8 v[4]; } h1;
    #pragma unroll
    for (int i = 0; i < 8; ++i) {
        h1.u[2*i]   = pack2bf(v1[i].x, v1[i].y);
        h1.u[2*i+1] = pack2bf(v1[i].z, v1[i].w);
    }

    bar_lds();   // bufA visible; index/count traffic may still fly

    unsigned short* st0 = DENSE ? (Hacc + (size_t)c0 * 128 * 64) : Hacc;
    unsigned short* st1 = DENSE ? (st0 + 128 * 64) : Hacc;

    // compute c0: X=bufA, scratch=bufB; park c1 rows into bufB near the end
    cluster_compute<true, DENSE>(bufA, bufB, ids0, bias0, Mtr, st0,
                                 lane, w, m, hk, r, cb,
                                 h1.v[0], h1.v[1], h1.v[2], h1.v[3]);

    bar_lds();   // all waves done reading bufA/bufB(c0); c1 X now in bufB.
                 // c0's stores intentionally still in flight.

    // compute c1: X=bufB, scratch=bufA
    short8 zz = {};
    cluster_compute<false, DENSE>(bufB, bufA, ids1, bias1, Mtr, st1,
                                  lane, w, m, hk, r, cb, zz, zz, zz, zz);
}

// Dense finalize: per node, gather its <=16 entries from H, sum in fp32,
// project through P via MFMA, divide by count, add x + bias.
__global__ __launch_bounds__(256, 4) void finalize_dense_kernel(
    const float* __restrict__ x_var, const float* __restrict__ x_clause,
    const unsigned short* __restrict__ H, const int* __restrict__ icnt,
    const int* __restrict__ buck, const unsigned short* __restrict__ Pbf,
    const float* __restrict__ bout, float* __restrict__ out)
{
    __shared__ int cnti[256];
    const int tid = threadIdx.x, lane = tid & 63, w = tid >> 6;
    const int base = blockIdx.x * 256;
    {
        int n = base + tid;
        cnti[tid] = (n < NN) ? icnt[n] : 0;
    }
    __syncthreads();

    const int m = lane & 31, hk = (lane >> 5) * 8;
    short8 pb[2][4];                              // P fragments via L1
    #pragma unroll
    for (int nt = 0; nt < 2; ++nt)
        #pragma unroll
        for (int ks = 0; ks < 4; ++ks)
            pb[nt][ks] = *(const short8*)(Pbf + (nt * 32 + m) * 64 + ks * 16 + hk);
    const float bias0 = bout[m], bias1 = bout[32 + m];

    #pragma unroll
    for (int tm = 0; tm < 2; ++tm) {
        int mt = w * 2 + tm;                      // rows base+mt*32 ..
        const int lr = mt * 32 + m;               // A-frag row for this lane
        const int na = base + lr;
        int cc = cnti[lr]; if (cc > BUCK_K) cc = BUCK_K;
        const int* bk = buck + (size_t)na * BUCK_K;

        floatx16 c0 = {}, c1 = {};
        #pragma unroll
        for (int ks = 0; ks < 4; ++ks) {
            float acc8[8] = {0.f,0.f,0.f,0.f,0.f,0.f,0.f,0.f};
            for (int j = 0; j < cc; ++j) {
                int e = bk[j];
                short8 hv = *(const short8*)(H + (size_t)e * 64 + ks * 16 + hk);
                #pragma unroll
                for (int q = 0; q < 8; ++q)
                    acc8[q] += bf2f((unsigned short)hv[q]);
            }
            short8 a;
            #pragma unroll
            for (int q = 0; q < 8; ++q) a[q] = (short)f2bf(acc8[q]);
            c0 = __builtin_amdgcn_mfma_f32_32x32x16_bf16(a, pb[0][ks], c0, 0, 0, 0);
            c1 = __builtin_amdgcn_mfma_f32_32x32x16_bf16(a, pb[1][ks], c1, 0, 0, 0);
        }
        #pragma unroll
        for (int rr = 0; rr < 16; ++rr) {
            int lrow = mt * 32 + crow(rr, lane);
            int n = base + lrow;
            if (n < NN) {
                float cf = (float)cnti[lrow];
                float inv = 1.0f / fmaxf(cf, 1.0f);
                const float* xs = (n < NV) ? (x_var + (size_t)n * 64)
                                           : (x_clause + (size_t)(n - NV) * 64);
                out[(size_t)n * 64 + m]      = xs[m]      + c0[rr] * inv + bias0;
                out[(size_t)n * 64 + 32 + m] = xs[32 + m] + c1[rr] * inv + bias1;
            }
        }
    }
}

// Fallback finalize (R9): accum_bf/countv produced by atomic scatter.
__global__ __launch_bounds__(256, 4) void finalize_kernel(
    const float* __restrict__ x_var, const float* __restrict__ x_clause,
    const unsigned short* __restrict__ accum_bf, const float* __restrict__ countv,
    const unsigned short* __restrict__ Pbf, const float* __restrict__ bout,
    float* __restrict__ out)
{
    __shared__ float cnts[256];
    const int tid = threadIdx.x, lane = tid & 63, w = tid >> 6;
    const int base = blockIdx.x * 256;
    {
        int n = base + tid;
        cnts[tid] = (n < NN) ? countv[n] : 1.f;
    }
    __syncthreads();

    const int m = lane & 31, hk = (lane >> 5) * 8;
    short8 pb[2][4];                              // P fragments via L1
    #pragma unroll
    for (int nt = 0; nt < 2; ++nt)
        #pragma unroll
        for (int ks = 0; ks < 4; ++ks)
            pb[nt][ks] = *(const short8*)(Pbf + (nt * 32 + m) * 64 + ks * 16 + hk);
    const float bias0 = bout[m], bias1 = bout[32 + m];

    #pragma unroll
    for (int tm = 0; tm < 2; ++tm) {
        int mt = w * 2 + tm;                      // rows base+mt*32 ..
        const unsigned short* arow = accum_bf + (size_t)(base + mt * 32 + m) * 64;
        floatx16 c0 = {}, c1 = {};
        #pragma unroll
        for (int ks = 0; ks < 4; ++ks) {
            short8 a = *(const short8*)(arow + ks * 16 + hk);
            c0 = __builtin_amdgcn_mfma_f32_32x32x16_bf16(a, pb[0][ks], c0, 0, 0, 0);
            c1 = __builtin_amdgcn_mfma_f32_32x32x16_bf16(a, pb[1][ks], c1, 0, 0, 0);
        }
        #pragma unroll
        for (int rr = 0; rr < 16; ++rr) {
            int lrow = mt * 32 + crow(rr, lane);
            int n = base + lrow;
            if (n < NN) {
                float inv = 1.0f / fmaxf(cnts[lrow], 1.0f);
                const float* xs = (n < NV) ? (x_var + (size_t)n * 64)
                                           : (x_clause + (size_t)(n - NV) * 64);
                out[(size_t)n * 64 + m]      = xs[m]      + c0[rr] * inv + bias0;
                out[(size_t)n * 64 + 32 + m] = xs[32 + m] + c1[rr] * inv + bias1;
            }
        }
    }
}

extern "C" void kernel_launch(void* const* d_in, const int* in_sizes, int n_in,
                              void* d_out, int out_size, void* d_ws, size_t ws_size,
                              hipStream_t stream)
{
    const float* x_var        = (const float*)d_in[0];
    const float* x_clause     = (const float*)d_in[1];
    const int*   cvar         = (const int*)d_in[4];
    const int*   ccl          = (const int*)d_in[5];
    const float* sat          = (const float*)d_in[6];
    const int*   active_heads = (const int*)d_in[7];
    const float* WQ           = (const float*)d_in[8];
    const float* WK           = (const float*)d_in[9];
    const float* WV           = (const float*)d_in[10];
    const float* head_weights = (const float*)d_in[11];
    const float* Wout         = (const float*)d_in[12];
    const float* bout         = (const float*)d_in[13];

    // ---- dense-path workspace layout ----
    const size_t H_BYTES    = (size_t)NCLUST * 128 * 64 * 2;   // 33,554,432
    const size_t ICNT_BYTES = 800256;                          // 200000*4 padded
    const size_t BUCK_BYTES = (size_t)NN * BUCK_K * 4;         // 12,800,000
    const size_t MTR_OFF    = H_BYTES + ICNT_BYTES + BUCK_BYTES;
    const size_t NEED       = MTR_OFF + 8192 + 8192;           // ~47.2 MB

    if (ws_size >= NEED) {
        unsigned short* H   = (unsigned short*)d_ws;
        int* icnt = (int*)((char*)d_ws + H_BYTES);
        int* buck = (int*)((char*)d_ws + H_BYTES + ICNT_BYTES);
        unsigned short* Mtr = (unsigned short*)((char*)d_ws + MTR_OFF);
        unsigned short* Pbf = Mtr + 4096;

        hipMemsetAsync(icnt, 0, (size_t)NN * 4, stream);
        prep_kernel<<<32, 256, 0, stream>>>(WQ, WK, WV, Wout, head_weights, active_heads, Mtr, Pbf);
        build_index_kernel<<<(NCLUST * 128) / 256, 256, 0, stream>>>(cvar, ccl, icnt, buck);
        attn_kernel<true><<<NCLUST / 2, 256, 0, stream>>>(
            x_var, x_clause, cvar, ccl, sat, Mtr, H, nullptr);
        finalize_dense_kernel<<<(NN + 255) / 256, 256, 0, stream>>>(
            x_var, x_clause, H, icnt, buck, Pbf, bout, (float*)d_out);
    } else {
        // ---- fallback: R9 atomic-scatter pipeline (27.2 MB ws) ----
        unsigned short* accum_bf = (unsigned short*)d_ws;          // NN*64 bf16
        float* countv = (float*)(accum_bf + (size_t)NN * 64);      // NN f32
        unsigned short* Mtr = (unsigned short*)(countv + NN);      // 4096 bf16
        unsigned short* Pbf = Mtr + 4096;                          // 4096 bf16

        hipMemsetAsync(accum_bf, 0, (size_t)NN * 64 * 2 + (size_t)NN * 4, stream);
        prep_kernel<<<32, 256, 0, stream>>>(WQ, WK, WV, Wout, head_weights, active_heads, Mtr, Pbf);
        attn_kernel<false><<<NCLUST / 2, 256, 0, stream>>>(
            x_var, x_clause, cvar, ccl, sat, Mtr, accum_bf, countv);
        finalize_kernel<<<(NN + 255) / 256, 256, 0, stream>>>(
            x_var, x_clause, accum_bf, countv, Pbf, bout, (float*)d_out);
    }
}

// Round 5
// 238.938 us; speedup vs baseline: 1.0108x; 1.0108x over previous
//
#include <hip/hip_runtime.h>

// IntraClusterGAT on MI355X — Round 11: CSR-slotted dense intermediate.
//   R10 lesson: dense-H killed attn atomics but finalize's bucket gather was
//   latency-serial (77µs, 0.75% MFMA, 3 blocks/CU). Fix: node-ordered G.
//     prep_count: Mtr/Pbf prep + per-entry icnt[nid]++           (1024 blocks)
//     scan:       off[n] = block-contiguous exclusive scan(icnt) (782 blocks)
//     attn:       slot = atomicAdd(cur[nid]) early (hidden); h-row -> plain
//                 128B store to G[slot]; NO pk-atomics, NO countv.
//     finalize:   block owns 128 consecutive nodes -> contiguous ~21KB G
//                 region (L2-local), cc~1.3 gather, fp32 sum -> MFMA @ P.
//   Fallback path (ws too small): exact R9 atomic-scatter pipeline.
// ws (dense): G 33.55MB | icnt+gbase 0.8MB | off 0.8MB | cur 0.8MB | Mtr/Pbf
//             16KB  = ~36MB.   ws (fallback): 27.2MB as R9.

#define NV 100000
#define NN 200000
#define NCLUST 2048
#define XS 72    // X/E row stride (bf16): 144B, 16B-aligned, conflict-free

typedef __attribute__((ext_vector_type(8))) short short8;
typedef __attribute__((ext_vector_type(16))) float floatx16;

__device__ __forceinline__ unsigned short f2bf(float f) {
    union { float f; unsigned u; } v; v.f = f;
    unsigned r = v.u + 0x7fffu + ((v.u >> 16) & 1u);   // RNE
    return (unsigned short)(r >> 16);
}
__device__ __forceinline__ float bf2f(unsigned short s) {
    union { unsigned u; float f; } v; v.u = (unsigned)s << 16; return v.f;
}
__device__ __forceinline__ unsigned pack2bf(float lo, float hi) {
    union { float f; unsigned u; } a, b; a.f = lo; b.f = hi;
    unsigned ra = a.u + 0x7fffu + ((a.u >> 16) & 1u);
    unsigned rb = b.u + 0x7fffu + ((b.u >> 16) & 1u);
    return (ra >> 16) | (rb & 0xffff0000u);
}
__device__ __forceinline__ int crow(int r, int lane) {   // MFMA 32x32 C row map
    return (r & 3) + 8 * (r >> 2) + 4 * (lane >> 5);
}
template<int CTRL>
__device__ __forceinline__ unsigned dppmov(unsigned v) {
    return (unsigned)__builtin_amdgcn_update_dpp(0, (int)v, CTRL, 0xf, 0xf, true);
}
template<int CTRL>
__device__ __forceinline__ float dppaddf(float s) {      // s + dpp_rotated(s)
    union { float f; unsigned u; } a, b; a.f = s;
    b.u = dppmov<CTRL>(a.u);
    return s + b.f;
}
__device__ __forceinline__ float dppxor1f(float s) {
    union { float f; unsigned u; } a, b; a.f = s;
    b.u = dppmov<0xB1>(a.u);
    return b.f;
}
// Barrier that orders LDS only: waves drain their own DS ops, then s_barrier.
// Global stores/atomics intentionally stay in flight.
__device__ __forceinline__ void bar_lds() {
    __builtin_amdgcn_sched_barrier(0);
    asm volatile("s_waitcnt lgkmcnt(0)" ::: "memory");
    __builtin_amdgcn_s_barrier();
    __builtin_amdgcn_sched_barrier(0);
}

// ---- prep (Mtr/Pbf) + per-entry node counting, merged: grid 1024x256 ----
__global__ __launch_bounds__(256) void prep_count_kernel(
    const float* __restrict__ WQ, const float* __restrict__ WK,
    const float* __restrict__ WV, const float* __restrict__ Wout,
    const float* __restrict__ head_weights, const int* __restrict__ active_heads_p,
    const int* __restrict__ cvar, const int* __restrict__ ccl,
    unsigned short* __restrict__ Mtr, unsigned short* __restrict__ Pbf,
    int* __restrict__ icnt)
{
    int o = blockIdx.x * blockDim.x + threadIdx.x;     // 0..262143
    if (o < 4096) {
        int d = o >> 6, a = o & 63;                    // Mtr[d][a] = M[a][d]
        float acc = 0.f;
        for (int j = 0; j < 64; ++j) acc += WQ[j*64 + a] * WK[j*64 + d];
        Mtr[o] = f2bf(acc * 0.125f);
    } else if (o < 8192) {
        int ah = active_heads_p[0];
        float hw = 0.f;
        for (int i = 0; i < ah; ++i) hw += head_weights[i];
        hw /= (float)ah;
        int o2 = o - 4096;
        int j = o2 >> 6, b = o2 & 63;                  // Pbf[j][b]
        float acc = 0.f;
        for (int d = 0; d < 64; ++d) acc += Wout[j*64 + d] * WV[d*64 + b];
        Pbf[o2] = f2bf(acc * hw);
    }
    // entry counting
    int c = o >> 7, r = o & 127;
    int nid = (r < 64) ? cvar[c * 64 + r] : (NV + ccl[c * 64 + (r - 64)]);
    atomicAdd(&icnt[nid], 1);
}

// Legacy prep for the fallback path.
__global__ __launch_bounds__(256) void prep_kernel(
    const float* __restrict__ WQ, const float* __restrict__ WK,
    const float* __restrict__ WV, const float* __restrict__ Wout,
    const float* __restrict__ head_weights, const int* __restrict__ active_heads_p,
    unsigned short* __restrict__ Mtr, unsigned short* __restrict__ Pbf)
{
    int o = blockIdx.x * blockDim.x + threadIdx.x;
    int ah = active_heads_p[0];
    float hw = 0.f;
    for (int i = 0; i < ah; ++i) hw += head_weights[i];
    hw /= (float)ah;
    if (o < 4096) {
        int d = o >> 6, a = o & 63;
        float acc = 0.f;
        for (int j = 0; j < 64; ++j) acc += WQ[j*64 + a] * WK[j*64 + d];
        Mtr[o] = f2bf(acc * 0.125f);
    } else if (o < 8192) {
        int o2 = o - 4096;
        int j = o2 >> 6, b = o2 & 63;
        float acc = 0.f;
        for (int d = 0; d < 64; ++d) acc += Wout[j*64 + d] * WV[d*64 + b];
        Pbf[o2] = f2bf(acc * hw);
    }
}

// ---- off[n]: block-contiguous exclusive scan of icnt; cur[n]=off[n] ----
__global__ __launch_bounds__(256) void scan_kernel(
    const int* __restrict__ icnt, int* __restrict__ off,
    int* __restrict__ cur, int* __restrict__ gbase)
{
    __shared__ int s[256];
    __shared__ int sbase;
    const int tid = threadIdx.x;
    const int n = blockIdx.x * 256 + tid;
    int c = (n < NN) ? icnt[n] : 0;
    s[tid] = c;
    __syncthreads();
    #pragma unroll
    for (int d = 1; d < 256; d <<= 1) {        // Hillis-Steele inclusive
        int v = (tid >= d) ? s[tid - d] : 0;
        __syncthreads();
        s[tid] += v;
        __syncthreads();
    }
    if (tid == 255) sbase = atomicAdd(gbase, s[255]);
    __syncthreads();
    int o = sbase + s[tid] - c;                // exclusive + block base
    if (n < NN) { off[n] = o; cur[n] = o; }
}

// Full per-cluster compute: GEMM1 -> GEMM2 -> softmax -> (E-half | GEMM3)x2
// -> [optional next-cluster X write into E buffer] -> h store.
// DENSE: ids[] holds G slot per row -> plain 128B-line store.
// else:  ids[] holds node id -> pk_add_bf16 atomic scatter.
template<bool WN, bool DENSE>
__device__ __forceinline__ void cluster_compute(
    unsigned short* X, unsigned short* E,
    const int* ids, const float* biascl,
    const unsigned short* __restrict__ Mtr,
    unsigned short* __restrict__ sbase,    // DENSE: G ; else accum_bf
    int lane, int w, int m, int hk, int r, int cb,
    short8 nx0, short8 nx1, short8 nx2, short8 nx3)
{
    // ---- GEMM1: Z = X @ M  (m-tile w, K=64; M frags from global/L1) ----
    {
        floatx16 z0 = {}, z1 = {};
        #pragma unroll
        for (int ks = 0; ks < 4; ++ks) {
            short8 mb0 = *(const short8*)(Mtr + m * 64 + ks * 16 + hk);
            short8 mb1 = *(const short8*)(Mtr + (32 + m) * 64 + ks * 16 + hk);
            short8 a = *(const short8*)&X[(w * 32 + m) * XS + ks * 16 + hk];
            z0 = __builtin_amdgcn_mfma_f32_32x32x16_bf16(a, mb0, z0, 0, 0, 0);
            z1 = __builtin_amdgcn_mfma_f32_32x32x16_bf16(a, mb1, z1, 0, 0, 0);
        }
        #pragma unroll
        for (int rr = 0; rr < 16; ++rr) {   // wave-local rows 32w..32w+31
            int row = w * 32 + crow(rr, lane);
            E[row * XS + m]      = f2bf(z0[rr]);
            E[row * XS + 32 + m] = f2bf(z1[rr]);
        }
    }

    // ---- GEMM2: scores = Z @ X^T  (m-tile w, n-tiles 0..3, K=64) ----
    floatx16 sc[4] = {{}, {}, {}, {}};
    #pragma unroll
    for (int ks = 0; ks < 4; ++ks) {
        short8 a = *(const short8*)&E[(w * 32 + m) * XS + ks * 16 + hk];
        #pragma unroll
        for (int nt = 0; nt < 4; ++nt) {
            short8 b = *(const short8*)&X[(nt * 32 + m) * XS + ks * 16 + hk];
            sc[nt] = __builtin_amdgcn_mfma_f32_32x32x16_bf16(a, b, sc[nt], 0, 0, 0);
        }
    }

    // ---- bias + leaky_relu + exp + rowsum (DPP ror x4 + 1 swizzle) ----
    const float b2 = biascl[m], b3 = biascl[32 + m];
    #pragma unroll
    for (int rr = 0; rr < 16; ++rr) {
        float a0 = sc[0][rr], a1 = sc[1][rr], a2 = sc[2][rr] + b2, a3 = sc[3][rr] + b3;
        a0 = a0 > 0.f ? a0 : 0.2f * a0;
        a1 = a1 > 0.f ? a1 : 0.2f * a1;
        a2 = a2 > 0.f ? a2 : 0.2f * a2;
        a3 = a3 > 0.f ? a3 : 0.2f * a3;
        a0 = __expf(a0); a1 = __expf(a1); a2 = __expf(a2); a3 = __expf(a3);
        float s4 = (a0 + a1) + (a2 + a3);       // row's 32-col partial per lane
        s4 = dppaddf<0x121>(s4);                // + ror1   (16-lane row, VALU)
        s4 = dppaddf<0x122>(s4);                // + ror2
        s4 = dppaddf<0x124>(s4);                // + ror4
        s4 = dppaddf<0x128>(s4);                // + ror8 -> 16-lane sum everywhere
        {   // cross-16 within each 32-lane half: one ds_swizzle xor16
            union { float f; int i; } t, o; t.f = s4;
            o.i = __builtin_amdgcn_ds_swizzle(t.i, 0x401F);
            s4 += o.f;
        }
        float inv = __builtin_amdgcn_rcpf(s4);  // full 128-col rowsum (half-wave)
        sc[0][rr] = a0 * inv; sc[1][rr] = a1 * inv;
        sc[2][rr] = a2 * inv; sc[3][rr] = a3 * inv;
    }

    // ---- E-half 1 (cols 0..63) over Z rows (wave-local; in-order DS) ----
    #pragma unroll
    for (int rr = 0; rr < 16; ++rr) {
        int row = w * 32 + crow(rr, lane);
        E[row * XS + m]      = f2bf(sc[0][rr]);
        E[row * XS + 32 + m] = f2bf(sc[1][rr]);
    }

    // ---- GEMM3: B col-pairs via b32 loads (-> ds_read2_b32) + v_perm ----
    const int cp = m & ~1;                       // col-pair base
    const unsigned selp = (lane & 1) ? 0x07060302u : 0x05040100u;  // hi16 : lo16
    floatx16 g0 = {}, g1 = {};
    #pragma unroll
    for (int ks = 0; ks < 4; ++ks) {             // half 1: t = 0..63
        short8 a = *(const short8*)&E[(w * 32 + m) * XS + ks * 16 + hk];
        const unsigned short* tb = &X[(ks * 16 + hk) * XS];
        unsigned q0[8], q1[8];
        #pragma unroll
        for (int u = 0; u < 8; ++u) {
            q0[u] = *(const unsigned*)(tb + u * XS + cp);
            q1[u] = *(const unsigned*)(tb + u * XS + cp + 32);
        }
        union { unsigned u[4]; short8 v; } b0, b1;
        b0.u[0] = __builtin_amdgcn_perm(q0[1], q0[0], selp);
        b0.u[1] = __builtin_amdgcn_perm(q0[3], q0[2], selp);
        b0.u[2] = __builtin_amdgcn_perm(q0[5], q0[4], selp);
        b0.u[3] = __builtin_amdgcn_perm(q0[7], q0[6], selp);
        b1.u[0] = __builtin_amdgcn_perm(q1[1], q1[0], selp);
        b1.u[1] = __builtin_amdgcn_perm(q1[3], q1[2], selp);
        b1.u[2] = __builtin_amdgcn_perm(q1[5], q1[4], selp);
        b1.u[3] = __builtin_amdgcn_perm(q1[7], q1[6], selp);
        g0 = __builtin_amdgcn_mfma_f32_32x32x16_bf16(a, b0.v, g0, 0, 0, 0);
        g1 = __builtin_amdgcn_mfma_f32_32x32x16_bf16(a, b1.v, g1, 0, 0, 0);
    }

    // ---- E-half 2 (cols 64..127) ----
    #pragma unroll
    for (int rr = 0; rr < 16; ++rr) {
        int row = w * 32 + crow(rr, lane);
        E[row * XS + m]      = f2bf(sc[2][rr]);
        E[row * XS + 32 + m] = f2bf(sc[3][rr]);
    }

    // ---- GEMM3 half 2: t = 64..127 ----
    #pragma unroll
    for (int ks = 0; ks < 4; ++ks) {
        short8 a = *(const short8*)&E[(w * 32 + m) * XS + ks * 16 + hk];
        const unsigned short* tb = &X[(64 + ks * 16 + hk) * XS];
        unsigned q0[8], q1[8];
        #pragma unroll
        for (int u = 0; u < 8; ++u) {
            q0[u] = *(const unsigned*)(tb + u * XS + cp);
            q1[u] = *(const unsigned*)(tb + u * XS + cp + 32);
        }
        union { unsigned u[4]; short8 v; } b0, b1;
        b0.u[0] = __builtin_amdgcn_perm(q0[1], q0[0], selp);
        b0.u[1] = __builtin_amdgcn_perm(q0[3], q0[2], selp);
        b0.u[2] = __builtin_amdgcn_perm(q0[5], q0[4], selp);
        b0.u[3] = __builtin_amdgcn_perm(q0[7], q0[6], selp);
        b1.u[0] = __builtin_amdgcn_perm(q1[1], q1[0], selp);
        b1.u[1] = __builtin_amdgcn_perm(q1[3], q1[2], selp);
        b1.u[2] = __builtin_amdgcn_perm(q1[5], q1[4], selp);
        b1.u[3] = __builtin_amdgcn_perm(q1[7], q1[6], selp);
        g0 = __builtin_amdgcn_mfma_f32_32x32x16_bf16(a, b0.v, g0, 0, 0, 0);
        g1 = __builtin_amdgcn_mfma_f32_32x32x16_bf16(a, b1.v, g1, 0, 0, 0);
    }

    // ---- park next cluster's X rows into E (wave-local rows; DS in-order
    //      guarantees these land after this wave's last E A-reads above) ----
    if (WN) {
        *(short8*)&E[r * XS + cb +  0] = nx0;
        *(short8*)&E[r * XS + cb +  8] = nx1;
        *(short8*)&E[r * XS + cb + 16] = nx2;
        *(short8*)&E[r * XS + cb + 24] = nx3;
    }

    // ---- pack adjacent cols (DPP quad_perm xor1) + h store ----
    const bool ev = !(lane & 1);
    const int colbase = ev ? m : (31 + m);
    #pragma unroll
    for (int rr = 0; rr < 16; ++rr) {
        int row = w * 32 + crow(rr, lane);
        float a0 = g0[rr], a1 = g1[rr];
        float t0 = dppxor1f(a0);
        float t1 = dppxor1f(a1);
        float lo = ev ? a0 : t1;
        float hi = ev ? t0 : a1;
        unsigned pk = (unsigned)f2bf(lo) | ((unsigned)f2bf(hi) << 16);
        if constexpr (DENSE) {
            int slot = ids[row];    // CSR slot; full-line plain store
            *(unsigned*)(sbase + (size_t)slot * 64 + colbase) = pk;
        } else {
            int nid = ids[row];
            unsigned long long addr =
                (unsigned long long)(sbase + (size_t)nid * 64 + colbase);
            asm volatile("global_atomic_pk_add_bf16 %0, %1, off"
                         :: "v"(addr), "v"(pk) : "memory");
        }
    }
}

template<bool DENSE>
__global__ __launch_bounds__(256, 4) void attn_kernel(
    const float* __restrict__ x_var, const float* __restrict__ x_clause,
    const int* __restrict__ cvar, const int* __restrict__ ccl,
    const float* __restrict__ sat, const unsigned short* __restrict__ Mtr,
    unsigned short* __restrict__ Hacc, float* __restrict__ countv,
    int* __restrict__ cur)
{
    __shared__ unsigned short bufA[128 * XS];  // 18432
    __shared__ unsigned short bufB[128 * XS];  // 18432
    __shared__ int   ids0[128], ids1[128];     // 1024  (slots in DENSE mode)
    __shared__ float bias0[64], bias1[64];     // 512
    // total 38400 B -> 4 blocks/CU

    const int tid = threadIdx.x, lane = tid & 63, w = tid >> 6;
    const int m = lane & 31, hk = (lane >> 5) * 8;
    const int c0 = blockIdx.x * 2;             // this block owns c0, c0+1
    const int r = tid >> 1, half = tid & 1, cb = half * 32;

    // ---- ids for BOTH clusters (issued together -> one latency) ----
    int nid0, nid1;
    const float *src0, *src1;
    float sv0 = 0.f, sv1 = 0.f;
    if (r < 64) {
        nid0 = cvar[c0 * 64 + r];
        nid1 = cvar[c0 * 64 + 64 + r];         // cluster c0+1
        src0 = x_var + (size_t)nid0 * 64;
        src1 = x_var + (size_t)nid1 * 64;
    } else {
        int cid0 = ccl[c0 * 64 + (r - 64)];
        int cid1 = ccl[c0 * 64 + r];           // cluster c0+1
        nid0 = NV + cid0; nid1 = NV + cid1;
        src0 = x_clause + (size_t)cid0 * 64;
        src1 = x_clause + (size_t)cid1 * 64;
        if (half) { sv0 = sat[cid0]; sv1 = sat[cid1]; }
    }

    // ---- issue ALL 16 row loads (both clusters) back-to-back ----
    const float4* s40 = (const float4*)src0 + half * 8;
    const float4* s41 = (const float4*)src1 + half * 8;
    float4 v0[8], v1[8];
    #pragma unroll
    for (int i = 0; i < 8; ++i) v0[i] = s40[i];
    #pragma unroll
    for (int i = 0; i < 8; ++i) v1[i] = s41[i];

    if (!half) {
        if constexpr (DENSE) {
            // claim CSR slots early; latency hidden under bf16 conversion
            ids0[r] = atomicAdd(&cur[nid0], 1);
            ids1[r] = atomicAdd(&cur[nid1], 1);
        } else {
            ids0[r] = nid0; ids1[r] = nid1;
            atomicAdd(&countv[nid0], 1.0f);
            atomicAdd(&countv[nid1], 1.0f);
        }
    }
    if (r >= 64 && half) { bias0[r - 64] = sv0; bias1[r - 64] = sv1; }

    // ---- c0 -> bufA (row-major bf16) ----
    {
        union { unsigned u[16]; short8 v[4]; } h0;
        #pragma unroll
        for (int i = 0; i < 8; ++i) {
            h0.u[2*i]   = pack2bf(v0[i].x, v0[i].y);
            h0.u[2*i+1] = pack2bf(v0[i].z, v0[i].w);
        }
        #pragma unroll
        for (int i = 0; i < 4; ++i) *(short8*)&bufA[r * XS + cb + i * 8] = h0.v[i];
    }
    // ---- c1 -> 16 packed VGPRs (held across c0 compute) ----
    union { unsigned u[16]; short8 v[4]; } h1;
    #pragma unroll
    for (int i = 0; i < 8; ++i) {
        h1.u[2*i]   = pack2bf(v1[i].x, v1[i].y);
        h1.u[2*i+1] = pack2bf(v1[i].z, v1[i].w);
    }

    bar_lds();   // bufA + ids visible; global traffic may still fly

    // compute c0: X=bufA, scratch=bufB; park c1 rows into bufB near the end
    cluster_compute<true, DENSE>(bufA, bufB, ids0, bias0, Mtr, Hacc,
                                 lane, w, m, hk, r, cb,
                                 h1.v[0], h1.v[1], h1.v[2], h1.v[3]);

    bar_lds();   // all waves done reading bufA/bufB(c0); c1 X now in bufB.
                 // c0's stores intentionally still in flight.

    // compute c1: X=bufB, scratch=bufA
    short8 zz = {};
    cluster_compute<false, DENSE>(bufB, bufA, ids1, bias1, Mtr, Hacc,
                                  lane, w, m, hk, r, cb, zz, zz, zz, zz);
}

// CSR finalize: block owns 128 consecutive nodes; their G rows form ONE
// contiguous region (scan is block-contiguous). fp32 sum -> MFMA @ P.
__global__ __launch_bounds__(256) void finalize_dense_kernel(
    const float* __restrict__ x_var, const float* __restrict__ x_clause,
    const unsigned short* __restrict__ G, const int* __restrict__ icnt,
    const int* __restrict__ off, const unsigned short* __restrict__ Pbf,
    const float* __restrict__ bout, float* __restrict__ out)
{
    __shared__ int scnt[128], soff[128];
    const int tid = threadIdx.x, lane = tid & 63, w = tid >> 6;
    const int base = blockIdx.x * 128;         // 128 nodes/block, wave w: rows w*32..
    if (tid < 128) {
        int n = base + tid;
        bool v = n < NN;
        scnt[tid] = v ? icnt[n] : 0;
        soff[tid] = v ? off[n] : 0;
    }
    __syncthreads();

    const int m = lane & 31, hk = (lane >> 5) * 8;
    short8 pb[2][4];                              // P fragments via L1
    #pragma unroll
    for (int nt = 0; nt < 2; ++nt)
        #pragma unroll
        for (int ks = 0; ks < 4; ++ks)
            pb[nt][ks] = *(const short8*)(Pbf + (nt * 32 + m) * 64 + ks * 16 + hk);
    const float bias0 = bout[m], bias1 = bout[32 + m];

    const int lr = w * 32 + m;                 // this lane's A-frag node row
    const int cc = scnt[lr];
    const int o  = soff[lr];

    float acc[4][8] = {};                      // fp32 sum over entries
    for (int j = 0; j < cc; ++j) {
        const unsigned short* row = G + (size_t)(o + j) * 64;
        #pragma unroll
        for (int ks = 0; ks < 4; ++ks) {       // 4 independent 16B loads / j
            short8 hv = *(const short8*)(row + ks * 16 + hk);
            #pragma unroll
            for (int q = 0; q < 8; ++q)
                acc[ks][q] += bf2f((unsigned short)hv[q]);
        }
    }

    floatx16 c0 = {}, c1 = {};
    #pragma unroll
    for (int ks = 0; ks < 4; ++ks) {
        short8 a;
        #pragma unroll
        for (int q = 0; q < 8; ++q) a[q] = (short)f2bf(acc[ks][q]);
        c0 = __builtin_amdgcn_mfma_f32_32x32x16_bf16(a, pb[0][ks], c0, 0, 0, 0);
        c1 = __builtin_amdgcn_mfma_f32_32x32x16_bf16(a, pb[1][ks], c1, 0, 0, 0);
    }
    #pragma unroll
    for (int rr = 0; rr < 16; ++rr) {
        int lrow = w * 32 + crow(rr, lane);
        int n = base + lrow;
        if (n < NN) {
            float inv = 1.0f / fmaxf((float)scnt[lrow], 1.0f);
            const float* xs = (n < NV) ? (x_var + (size_t)n * 64)
                                       : (x_clause + (size_t)(n - NV) * 64);
            out[(size_t)n * 64 + m]      = xs[m]      + c0[rr] * inv + bias0;
            out[(size_t)n * 64 + 32 + m] = xs[32 + m] + c1[rr] * inv + bias1;
        }
    }
}

// Fallback finalize (R9): accum_bf/countv produced by atomic scatter.
__global__ __launch_bounds__(256, 4) void finalize_kernel(
    const float* __restrict__ x_var, const float* __restrict__ x_clause,
    const unsigned short* __restrict__ accum_bf, const float* __restrict__ countv,
    const unsigned short* __restrict__ Pbf, const float* __restrict__ bout,
    float* __restrict__ out)
{
    __shared__ float cnts[256];
    const int tid = threadIdx.x, lane = tid & 63, w = tid >> 6;
    const int base = blockIdx.x * 256;
    {
        int n = base + tid;
        cnts[tid] = (n < NN) ? countv[n] : 1.f;
    }
    __syncthreads();

    const int m = lane & 31, hk = (lane >> 5) * 8;
    short8 pb[2][4];
    #pragma unroll
    for (int nt = 0; nt < 2; ++nt)
        #pragma unroll
        for (int ks = 0; ks < 4; ++ks)
            pb[nt][ks] = *(const short8*)(Pbf + (nt * 32 + m) * 64 + ks * 16 + hk);
    const float bias0 = bout[m], bias1 = bout[32 + m];

    #pragma unroll
    for (int tm = 0; tm < 2; ++tm) {
        int mt = w * 2 + tm;
        const unsigned short* arow = accum_bf + (size_t)(base + mt * 32 + m) * 64;
        floatx16 c0 = {}, c1 = {};
        #pragma unroll
        for (int ks = 0; ks < 4; ++ks) {
            short8 a = *(const short8*)(arow + ks * 16 + hk);
            c0 = __builtin_amdgcn_mfma_f32_32x32x16_bf16(a, pb[0][ks], c0, 0, 0, 0);
            c1 = __builtin_amdgcn_mfma_f32_32x32x16_bf16(a, pb[1][ks], c1, 0, 0, 0);
        }
        #pragma unroll
        for (int rr = 0; rr < 16; ++rr) {
            int lrow = mt * 32 + crow(rr, lane);
            int n = base + lrow;
            if (n < NN) {
                float inv = 1.0f / fmaxf(cnts[lrow], 1.0f);
                const float* xs = (n < NV) ? (x_var + (size_t)n * 64)
                                           : (x_clause + (size_t)(n - NV) * 64);
                out[(size_t)n * 64 + m]      = xs[m]      + c0[rr] * inv + bias0;
                out[(size_t)n * 64 + 32 + m] = xs[32 + m] + c1[rr] * inv + bias1;
            }
        }
    }
}

extern "C" void kernel_launch(void* const* d_in, const int* in_sizes, int n_in,
                              void* d_out, int out_size, void* d_ws, size_t ws_size,
                              hipStream_t stream)
{
    const float* x_var        = (const float*)d_in[0];
    const float* x_clause     = (const float*)d_in[1];
    const int*   cvar         = (const int*)d_in[4];
    const int*   ccl          = (const int*)d_in[5];
    const float* sat          = (const float*)d_in[6];
    const int*   active_heads = (const int*)d_in[7];
    const float* WQ           = (const float*)d_in[8];
    const float* WK           = (const float*)d_in[9];
    const float* WV           = (const float*)d_in[10];
    const float* head_weights = (const float*)d_in[11];
    const float* Wout         = (const float*)d_in[12];
    const float* bout         = (const float*)d_in[13];

    // ---- CSR dense-path workspace layout ----
    const size_t G_BYTES   = (size_t)NCLUST * 128 * 64 * 2;    // 33,554,432
    const size_t ICNT_OFF  = G_BYTES;                          // icnt[NN] + gbase
    const size_t GBASE_OFF = ICNT_OFF + (size_t)NN * 4;        // right after icnt
    const size_t OFF_OFF   = ICNT_OFF + 800256;
    const size_t CUR_OFF   = OFF_OFF + 800256;
    const size_t MTR_OFF   = CUR_OFF + 800256;
    const size_t NEED      = MTR_OFF + 8192 + 8192;            // ~36 MB

    if (ws_size >= NEED) {
        unsigned short* G   = (unsigned short*)d_ws;
        int* icnt  = (int*)((char*)d_ws + ICNT_OFF);
        int* gbase = (int*)((char*)d_ws + GBASE_OFF);
        int* off   = (int*)((char*)d_ws + OFF_OFF);
        int* cur   = (int*)((char*)d_ws + CUR_OFF);
        unsigned short* Mtr = (unsigned short*)((char*)d_ws + MTR_OFF);
        unsigned short* Pbf = Mtr + 4096;

        hipMemsetAsync(icnt, 0, (size_t)NN * 4 + 256, stream);   // icnt + gbase
        prep_count_kernel<<<1024, 256, 0, stream>>>(
            WQ, WK, WV, Wout, head_weights, active_heads, cvar, ccl, Mtr, Pbf, icnt);
        scan_kernel<<<(NN + 255) / 256, 256, 0, stream>>>(icnt, off, cur, gbase);
        attn_kernel<true><<<NCLUST / 2, 256, 0, stream>>>(
            x_var, x_clause, cvar, ccl, sat, Mtr, G, nullptr, cur);
        finalize_dense_kernel<<<(NN + 127) / 128, 256, 0, stream>>>(
            x_var, x_clause, G, icnt, off, Pbf, bout, (float*)d_out);
    } else {
        // ---- fallback: R9 atomic-scatter pipeline (27.2 MB ws) ----
        unsigned short* accum_bf = (unsigned short*)d_ws;          // NN*64 bf16
        float* countv = (float*)(accum_bf + (size_t)NN * 64);      // NN f32
        unsigned short* Mtr = (unsigned short*)(countv + NN);      // 4096 bf16
        unsigned short* Pbf = Mtr + 4096;                          // 4096 bf16

        hipMemsetAsync(accum_bf, 0, (size_t)NN * 64 * 2 + (size_t)NN * 4, stream);
        prep_kernel<<<32, 256, 0, stream>>>(WQ, WK, WV, Wout, head_weights, active_heads, Mtr, Pbf);
        attn_kernel<false><<<NCLUST / 2, 256, 0, stream>>>(
            x_var, x_clause, cvar, ccl, sat, Mtr, accum_bf, nullptr, nullptr);
        finalize_kernel<<<(NN + 255) / 256, 256, 0, stream>>>(
            x_var, x_clause, accum_bf, countv, Pbf, bout, (float*)d_out);
    }
}

// Round 6
// 209.748 us; speedup vs baseline: 1.1515x; 1.1392x over previous
//
#include <hip/hip_runtime.h>

// IntraClusterGAT on MI355X — Round 12: revert attn to R8 (best measured,
// 57.7µs); attack the never-profiled finalize + dispatch count.
//   prep:  Mtr/Pbf weights + grid-stride zeroing of accum_bf/countv
//          (memset dispatch eliminated; 3 dispatches total)
//   attn:  R8 ping-pong 2-cluster pipeline, byte-identical compute
//   final: MFMA as before, but epilogue via wave-private LDS transpose:
//          stage c*inv+bias to T[32][68] f32 (conflict-free, wave-local,
//          in-order DS -> no barrier), then read back as float4 and do
//          x-add + out-store as 8+8 float4 ops/lane instead of 64+64
//          scalar 4B ops. Same bytes, 4x fewer global instrs, deeper MLP.
// ws: accum_bf[NN*64] bf16 | countv[NN] f32 | Mtr 4096 bf16 | Pbf 4096 bf16

#define NV 100000
#define NN 200000
#define NCLUST 2048
#define XS 72    // X/E row stride (bf16): 144B, 16B-aligned, conflict-free

typedef __attribute__((ext_vector_type(8))) short short8;
typedef __attribute__((ext_vector_type(16))) float floatx16;
typedef __attribute__((ext_vector_type(4))) unsigned uint4v;

__device__ __forceinline__ unsigned short f2bf(float f) {
    union { float f; unsigned u; } v; v.f = f;
    unsigned r = v.u + 0x7fffu + ((v.u >> 16) & 1u);   // RNE
    return (unsigned short)(r >> 16);
}
__device__ __forceinline__ unsigned pack2bf(float lo, float hi) {
    union { float f; unsigned u; } a, b; a.f = lo; b.f = hi;
    unsigned ra = a.u + 0x7fffu + ((a.u >> 16) & 1u);
    unsigned rb = b.u + 0x7fffu + ((b.u >> 16) & 1u);
    return (ra >> 16) | (rb & 0xffff0000u);
}
__device__ __forceinline__ int crow(int r, int lane) {   // MFMA 32x32 C row map
    return (r & 3) + 8 * (r >> 2) + 4 * (lane >> 5);
}
// Barrier that orders LDS only: waves drain their own DS ops, then s_barrier.
// Global atomics (accum scatter, countv) intentionally stay in flight.
__device__ __forceinline__ void bar_lds() {
    __builtin_amdgcn_sched_barrier(0);
    asm volatile("s_waitcnt lgkmcnt(0)" ::: "memory");
    __builtin_amdgcn_s_barrier();
    __builtin_amdgcn_sched_barrier(0);
}

// ---- prep: Mtr/Pbf weights + zero accum_bf/countv (replaces memset) ----
#define ZU4 1650000   // (NN*64*2 + NN*4) / 16 bytes -> uint4 count
__global__ __launch_bounds__(256) void prep_kernel(
    const float* __restrict__ WQ, const float* __restrict__ WK,
    const float* __restrict__ WV, const float* __restrict__ Wout,
    const float* __restrict__ head_weights, const int* __restrict__ active_heads_p,
    unsigned short* __restrict__ Mtr, unsigned short* __restrict__ Pbf,
    uint4v* __restrict__ zbase)
{
    int o = blockIdx.x * blockDim.x + threadIdx.x;
    if (o < 4096) {
        int d = o >> 6, a = o & 63;                       // Mtr[d][a] = M[a][d]
        float acc = 0.f;
        for (int j = 0; j < 64; ++j) acc += WQ[j*64 + a] * WK[j*64 + d];
        Mtr[o] = f2bf(acc * 0.125f);
    } else if (o < 8192) {
        int ah = active_heads_p[0];
        float hw = 0.f;
        for (int i = 0; i < ah; ++i) hw += head_weights[i];
        hw /= (float)ah;
        int o2 = o - 4096;
        int j = o2 >> 6, b = o2 & 63;                     // Pbf[j][b]
        float acc = 0.f;
        for (int d = 0; d < 64; ++d) acc += Wout[j*64 + d] * WV[d*64 + b];
        Pbf[o2] = f2bf(acc * hw);
    }
    // grid-stride zero of accum_bf + countv (contiguous, 16B-multiple)
    uint4v z = {0u, 0u, 0u, 0u};
    for (int j = o; j < ZU4; j += 262144) zbase[j] = z;
}

// Full per-cluster compute (R8-exact): GEMM1 -> GEMM2 -> softmax ->
// (E-half | GEMM3)x2 -> [optional next-cluster X park] -> atomic scatter.
template<bool WN>
__device__ __forceinline__ void cluster_compute(
    unsigned short* X, unsigned short* E,
    const int* ids, const float* biascl,
    const unsigned short* __restrict__ Mtr,
    unsigned short* __restrict__ accum_bf,
    int lane, int w, int m, int hk, int r, int cb,
    short8 nx0, short8 nx1, short8 nx2, short8 nx3)
{
    // ---- GEMM1: Z = X @ M  (m-tile w, K=64; M frags from global/L1) ----
    {
        floatx16 z0 = {}, z1 = {};
        #pragma unroll
        for (int ks = 0; ks < 4; ++ks) {
            short8 mb0 = *(const short8*)(Mtr + m * 64 + ks * 16 + hk);
            short8 mb1 = *(const short8*)(Mtr + (32 + m) * 64 + ks * 16 + hk);
            short8 a = *(const short8*)&X[(w * 32 + m) * XS + ks * 16 + hk];
            z0 = __builtin_amdgcn_mfma_f32_32x32x16_bf16(a, mb0, z0, 0, 0, 0);
            z1 = __builtin_amdgcn_mfma_f32_32x32x16_bf16(a, mb1, z1, 0, 0, 0);
        }
        #pragma unroll
        for (int rr = 0; rr < 16; ++rr) {   // wave-local rows 32w..32w+31
            int row = w * 32 + crow(rr, lane);
            E[row * XS + m]      = f2bf(z0[rr]);
            E[row * XS + 32 + m] = f2bf(z1[rr]);
        }
    }

    // ---- GEMM2: scores = Z @ X^T  (m-tile w, n-tiles 0..3, K=64) ----
    floatx16 sc[4] = {{}, {}, {}, {}};
    #pragma unroll
    for (int ks = 0; ks < 4; ++ks) {
        short8 a = *(const short8*)&E[(w * 32 + m) * XS + ks * 16 + hk];
        #pragma unroll
        for (int nt = 0; nt < 4; ++nt) {
            short8 b = *(const short8*)&X[(nt * 32 + m) * XS + ks * 16 + hk];
            sc[nt] = __builtin_amdgcn_mfma_f32_32x32x16_bf16(a, b, sc[nt], 0, 0, 0);
        }
    }

    // ---- bias + leaky_relu + exp + rowsum(shfl) + normalize (all fp32) ----
    const float b2 = biascl[m], b3 = biascl[32 + m];
    #pragma unroll
    for (int rr = 0; rr < 16; ++rr) {
        float a0 = sc[0][rr], a1 = sc[1][rr], a2 = sc[2][rr] + b2, a3 = sc[3][rr] + b3;
        a0 = a0 > 0.f ? a0 : 0.2f * a0;
        a1 = a1 > 0.f ? a1 : 0.2f * a1;
        a2 = a2 > 0.f ? a2 : 0.2f * a2;
        a3 = a3 > 0.f ? a3 : 0.2f * a3;
        a0 = __expf(a0); a1 = __expf(a1); a2 = __expf(a2); a3 = __expf(a3);
        float s4 = (a0 + a1) + (a2 + a3);       // row's 32-col partial per lane
        #pragma unroll
        for (int off = 1; off < 32; off <<= 1) s4 += __shfl_xor(s4, off, 64);
        float inv = __builtin_amdgcn_rcpf(s4);  // full 128-col rowsum (half-wave)
        sc[0][rr] = a0 * inv; sc[1][rr] = a1 * inv;
        sc[2][rr] = a2 * inv; sc[3][rr] = a3 * inv;
    }

    // ---- E-half 1 (cols 0..63) over Z rows (wave-local; in-order DS) ----
    #pragma unroll
    for (int rr = 0; rr < 16; ++rr) {
        int row = w * 32 + crow(rr, lane);
        E[row * XS + m]      = f2bf(sc[0][rr]);
        E[row * XS + 32 + m] = f2bf(sc[1][rr]);
    }

    // ---- GEMM3 half 1: t = 0..63 (B cols via ds_read_u16 from X) ----
    floatx16 g0 = {}, g1 = {};
    #pragma unroll
    for (int ks = 0; ks < 4; ++ks) {
        short8 a = *(const short8*)&E[(w * 32 + m) * XS + ks * 16 + hk];
        short8 b0, b1;
        #pragma unroll
        for (int j = 0; j < 8; ++j) {
            int t = ks * 16 + hk + j;
            b0[j] = (short)X[t * XS + m];
            b1[j] = (short)X[t * XS + 32 + m];
        }
        g0 = __builtin_amdgcn_mfma_f32_32x32x16_bf16(a, b0, g0, 0, 0, 0);
        g1 = __builtin_amdgcn_mfma_f32_32x32x16_bf16(a, b1, g1, 0, 0, 0);
    }

    // ---- E-half 2 (cols 64..127) ----
    #pragma unroll
    for (int rr = 0; rr < 16; ++rr) {
        int row = w * 32 + crow(rr, lane);
        E[row * XS + m]      = f2bf(sc[2][rr]);
        E[row * XS + 32 + m] = f2bf(sc[3][rr]);
    }

    // ---- GEMM3 half 2: t = 64..127 ----
    #pragma unroll
    for (int ks = 0; ks < 4; ++ks) {
        short8 a = *(const short8*)&E[(w * 32 + m) * XS + ks * 16 + hk];
        short8 b0, b1;
        #pragma unroll
        for (int j = 0; j < 8; ++j) {
            int t = 64 + ks * 16 + hk + j;
            b0[j] = (short)X[t * XS + m];
            b1[j] = (short)X[t * XS + 32 + m];
        }
        g0 = __builtin_amdgcn_mfma_f32_32x32x16_bf16(a, b0, g0, 0, 0, 0);
        g1 = __builtin_amdgcn_mfma_f32_32x32x16_bf16(a, b1, g1, 0, 0, 0);
    }

    // ---- park next cluster's X rows into E (wave-local rows; DS in-order
    //      guarantees these land after this wave's last E A-reads above) ----
    if (WN) {
        *(short8*)&E[r * XS + cb +  0] = nx0;
        *(short8*)&E[r * XS + cb +  8] = nx1;
        *(short8*)&E[r * XS + cb + 16] = nx2;
        *(short8*)&E[r * XS + cb + 24] = nx3;
    }

    // ---- pack adjacent cols (shfl_xor 1) + pk_add_bf16 scatter ----
    const bool ev = !(lane & 1);
    const int colbase = ev ? m : (31 + m);
    #pragma unroll
    for (int rr = 0; rr < 16; ++rr) {
        int row = w * 32 + crow(rr, lane);
        int nid = ids[row];
        float a0 = g0[rr], a1 = g1[rr];
        float t0 = __shfl_xor(a0, 1, 64);
        float t1 = __shfl_xor(a1, 1, 64);
        float lo = ev ? a0 : t1;
        float hi = ev ? t0 : a1;
        unsigned pk = (unsigned)f2bf(lo) | ((unsigned)f2bf(hi) << 16);
        unsigned long long addr =
            (unsigned long long)(accum_bf + (size_t)nid * 64 + colbase);
        asm volatile("global_atomic_pk_add_bf16 %0, %1, off"
                     :: "v"(addr), "v"(pk) : "memory");
    }
}

__global__ __launch_bounds__(256, 4) void attn_kernel(
    const float* __restrict__ x_var, const float* __restrict__ x_clause,
    const int* __restrict__ cvar, const int* __restrict__ ccl,
    const float* __restrict__ sat, const unsigned short* __restrict__ Mtr,
    unsigned short* __restrict__ accum_bf, float* __restrict__ countv)
{
    __shared__ unsigned short bufA[128 * XS];  // 18432
    __shared__ unsigned short bufB[128 * XS];  // 18432
    __shared__ int   ids0[128], ids1[128];     // 1024
    __shared__ float bias0[64], bias1[64];     // 512
    // total 38400 B -> 4 blocks/CU

    const int tid = threadIdx.x, lane = tid & 63, w = tid >> 6;
    const int m = lane & 31, hk = (lane >> 5) * 8;
    const int c0 = blockIdx.x * 2;             // this block owns c0, c0+1
    const int r = tid >> 1, half = tid & 1, cb = half * 32;

    // ---- ids for BOTH clusters (issued together -> one latency) ----
    int nid0, nid1;
    const float *src0, *src1;
    float sv0 = 0.f, sv1 = 0.f;
    if (r < 64) {
        nid0 = cvar[c0 * 64 + r];
        nid1 = cvar[c0 * 64 + 64 + r];         // cluster c0+1
        src0 = x_var + (size_t)nid0 * 64;
        src1 = x_var + (size_t)nid1 * 64;
    } else {
        int cid0 = ccl[c0 * 64 + (r - 64)];
        int cid1 = ccl[c0 * 64 + r];           // cluster c0+1
        nid0 = NV + cid0; nid1 = NV + cid1;
        src0 = x_clause + (size_t)cid0 * 64;
        src1 = x_clause + (size_t)cid1 * 64;
        if (half) { sv0 = sat[cid0]; sv1 = sat[cid1]; }
    }

    // ---- issue ALL 16 row loads (both clusters) back-to-back ----
    const float4* s40 = (const float4*)src0 + half * 8;
    const float4* s41 = (const float4*)src1 + half * 8;
    float4 v0[8], v1[8];
    #pragma unroll
    for (int i = 0; i < 8; ++i) v0[i] = s40[i];
    #pragma unroll
    for (int i = 0; i < 8; ++i) v1[i] = s41[i];

    if (!half) {
        ids0[r] = nid0; ids1[r] = nid1;
        atomicAdd(&countv[nid0], 1.0f);
        atomicAdd(&countv[nid1], 1.0f);
    }
    if (r >= 64 && half) { bias0[r - 64] = sv0; bias1[r - 64] = sv1; }

    // ---- c0 -> bufA (row-major bf16) ----
    {
        union { unsigned u[16]; short8 v[4]; } h0;
        #pragma unroll
        for (int i = 0; i < 8; ++i) {
            h0.u[2*i]   = pack2bf(v0[i].x, v0[i].y);
            h0.u[2*i+1] = pack2bf(v0[i].z, v0[i].w);
        }
        #pragma unroll
        for (int i = 0; i < 4; ++i) *(short8*)&bufA[r * XS + cb + i * 8] = h0.v[i];
    }
    // ---- c1 -> 16 packed VGPRs (held across c0 compute) ----
    union { unsigned u[16]; short8 v[4]; } h1;
    #pragma unroll
    for (int i = 0; i < 8; ++i) {
        h1.u[2*i]   = pack2bf(v1[i].x, v1[i].y);
        h1.u[2*i+1] = pack2bf(v1[i].z, v1[i].w);
    }

    bar_lds();   // bufA visible; countv/ids atomics may still fly

    // compute c0: X=bufA, scratch=bufB; park c1 rows into bufB near the end
    cluster_compute<true>(bufA, bufB, ids0, bias0, Mtr, accum_bf,
                          lane, w, m, hk, r, cb,
                          h1.v[0], h1.v[1], h1.v[2], h1.v[3]);

    bar_lds();   // all waves done reading bufA/bufB(c0); c1 X now in bufB.
                 // c0's atomic scatter intentionally still in flight.

    // compute c1: X=bufB, scratch=bufA
    short8 zz = {};
    cluster_compute<false>(bufB, bufA, ids1, bias1, Mtr, accum_bf,
                           lane, w, m, hk, r, cb, zz, zz, zz, zz);
}

// finalize v3: MFMA as before; epilogue via wave-private LDS transpose so
// x-add + out-store run as float4 (8+8 ops/lane/tile vs 64+64 scalar).
// T stride 68 f32: row base 272B (16B-aligned), b128 reads at bank floor.
__global__ __launch_bounds__(256, 4) void finalize_kernel(
    const float* __restrict__ x_var, const float* __restrict__ x_clause,
    const unsigned short* __restrict__ accum_bf, const float* __restrict__ countv,
    const unsigned short* __restrict__ Pbf, const float* __restrict__ bout,
    float* __restrict__ out)
{
    __shared__ float T[4][32][68];   // 34816B, one 32x64 tile per wave
    __shared__ float cnts[256];      //  1024B -> total 35840 -> 4 blocks/CU
    const int tid = threadIdx.x, lane = tid & 63, w = tid >> 6;
    const int base = blockIdx.x * 256;
    {
        int n = base + tid;
        cnts[tid] = (n < NN) ? countv[n] : 1.f;
    }
    __syncthreads();

    const int m = lane & 31, hk = (lane >> 5) * 8;
    short8 pb[2][4];                              // P fragments via L1
    #pragma unroll
    for (int nt = 0; nt < 2; ++nt)
        #pragma unroll
        for (int ks = 0; ks < 4; ++ks)
            pb[nt][ks] = *(const short8*)(Pbf + (nt * 32 + m) * 64 + ks * 16 + hk);
    const float bias0 = bout[m], bias1 = bout[32 + m];

    const int r2 = lane >> 1, cb2 = (lane & 1) * 32;   // phase-B mapping

    #pragma unroll
    for (int tm = 0; tm < 2; ++tm) {
        int mt = w * 2 + tm;                      // rows base+mt*32 ..
        const unsigned short* arow = accum_bf + (size_t)(base + mt * 32 + m) * 64;
        floatx16 c0 = {}, c1 = {};
        #pragma unroll
        for (int ks = 0; ks < 4; ++ks) {
            short8 a = *(const short8*)(arow + ks * 16 + hk);
            c0 = __builtin_amdgcn_mfma_f32_32x32x16_bf16(a, pb[0][ks], c0, 0, 0, 0);
            c1 = __builtin_amdgcn_mfma_f32_32x32x16_bf16(a, pb[1][ks], c1, 0, 0, 0);
        }
        // ---- phase A: stage (c*inv + bias) to wave-private T ----
        #pragma unroll
        for (int rr = 0; rr < 16; ++rr) {
            int lr32 = crow(rr, lane);            // 0..31 within tile
            float inv = 1.0f / fmaxf(cnts[mt * 32 + lr32], 1.0f);
            T[w][lr32][m]      = c0[rr] * inv + bias0;
            T[w][lr32][32 + m] = c1[rr] * inv + bias1;
        }
        // wave-local DS is in-order: reads below see this wave's writes.
        // ---- phase B: float4 x-add + out-store (2 rows per lane-pair) ----
        int n2 = base + mt * 32 + r2;
        if (n2 < NN) {
            const float* xr = (n2 < NV) ? (x_var + (size_t)n2 * 64)
                                        : (x_clause + (size_t)(n2 - NV) * 64);
            float* orow = out + (size_t)n2 * 64;
            #pragma unroll
            for (int j = 0; j < 8; ++j) {
                float4 t = *(const float4*)&T[w][r2][cb2 + 4 * j];
                float4 xv = *(const float4*)&xr[cb2 + 4 * j];
                float4 o;
                o.x = t.x + xv.x; o.y = t.y + xv.y;
                o.z = t.z + xv.z; o.w = t.w + xv.w;
                *(float4*)&orow[cb2 + 4 * j] = o;
            }
        }
    }
}

extern "C" void kernel_launch(void* const* d_in, const int* in_sizes, int n_in,
                              void* d_out, int out_size, void* d_ws, size_t ws_size,
                              hipStream_t stream)
{
    const float* x_var        = (const float*)d_in[0];
    const float* x_clause     = (const float*)d_in[1];
    const int*   cvar         = (const int*)d_in[4];
    const int*   ccl          = (const int*)d_in[5];
    const float* sat          = (const float*)d_in[6];
    const int*   active_heads = (const int*)d_in[7];
    const float* WQ           = (const float*)d_in[8];
    const float* WK           = (const float*)d_in[9];
    const float* WV           = (const float*)d_in[10];
    const float* head_weights = (const float*)d_in[11];
    const float* Wout         = (const float*)d_in[12];
    const float* bout         = (const float*)d_in[13];

    unsigned short* accum_bf = (unsigned short*)d_ws;          // NN*64 bf16
    float* countv = (float*)(accum_bf + (size_t)NN * 64);      // NN f32
    unsigned short* Mtr = (unsigned short*)(countv + NN);      // 4096 bf16
    unsigned short* Pbf = Mtr + 4096;                          // 4096 bf16

    // prep zeroes accum_bf+countv itself (26.4MB contiguous) -> no memset
    prep_kernel<<<1024, 256, 0, stream>>>(WQ, WK, WV, Wout, head_weights,
                                          active_heads, Mtr, Pbf,
                                          (uint4v*)d_ws);
    attn_kernel<<<NCLUST / 2, 256, 0, stream>>>(
        x_var, x_clause, cvar, ccl, sat, Mtr, accum_bf, countv);
    finalize_kernel<<<(NN + 255) / 256, 256, 0, stream>>>(
        x_var, x_clause, accum_bf, countv, Pbf, bout, (float*)d_out);
}